// Round 1
// 471.785 us; speedup vs baseline: 1.0083x; 1.0083x over previous
//
#include <hip/hip_runtime.h>

// TorchSAT: summed-area-table rectangle sampling.
// sat: (512,512,288) fp32, x: (N,4) fp32 -> out: (N,288) fp32.
// One wave per output row; all per-row case logic is wave-uniform.
//
// R4: separable cross-product decomposition. A SAT rectangle query is
//   (sum_u +-S) (x) (sum_v +-S), and the wrap cases share axis difference
//   operators, so every case is u-list (x) v-list with
//     u-list = {neu:+, nsu-du:-} (+ {bru:+} iff u wraps)
//     v-list = {nev:+, nsv-dv:-} (+ {brv:+} iff v wraps).
//   Corners at tlu-du / tlv-dv are statically OOB (== 0) and are no longer
//   issued: avg issued samples 9 -> 6.25, and the double-wrap case drops
//   from two dependent load batches to one gather<9>.
// Also: wave-uniform sample offsets go through readfirstlane (SGPR base +
// lane voffset addressing), dead tail-mask multiply removed.

constexpr int Hdim = 512;
constexpr int Wdim = 512;
constexpr int Cdim = 288;

typedef float f32x4 __attribute__((ext_vector_type(4)));

// Per-axis corner prep: coordinate -> texel index + effective sign (0 if OOB).
// u in [-1/512, 1): idx = floor(u*512 - 0.5) in [-2, 511]; only low-side OOB
// is possible, caught by the unsigned compare.
__device__ __forceinline__ void axis_prep(float u, float s, int& idx, float& sgn) {
    int i = (int)floorf(u * 512.0f - 0.5f);
    bool ok = (unsigned)i < 512u;
    idx = ok ? i : 0;
    sgn = ok ? s : 0.0f;
}

// Issue K samples' loads back-to-back (deep MLP), then accumulate.
// Offsets are wave-uniform -> readfirstlane pins them to SGPRs so each load
// is global_load_dwordx4 with scalar base + lane byte-offset.
// widx = (lane&7)+64 keeps the 288-float tail load in-row and non-divergent;
// lanes >= 8 accumulate a dead acc_b that is never stored.
template <int K>
__device__ __forceinline__ void gather(const float* __restrict__ sat,
                                       const int* off, const float* sgn,
                                       int lane, int widx,
                                       f32x4& a, f32x4& b) {
    f32x4 v[K], w[K];
#pragma unroll
    for (int k = 0; k < K; ++k) {
        int offk = __builtin_amdgcn_readfirstlane(off[k]);
        const f32x4* __restrict__ row = (const f32x4*)(sat + offk);
        v[k] = row[lane];
        w[k] = row[widx];
    }
#pragma unroll
    for (int k = 0; k < K; ++k) {
        float s = sgn[k];
        a += s * v[k];
        b += s * w[k];
    }
}

// Cross product of NU u-corners and NV v-corners -> NU*NV samples.
template <int NU, int NV>
__device__ __forceinline__ void run_case(const float* __restrict__ sat,
                                         const int* iu, const float* fu,
                                         const int* iv, const float* fv,
                                         int lane, int widx,
                                         f32x4& a, f32x4& b) {
    int off[NU * NV];
    float sgn[NU * NV];
#pragma unroll
    for (int i = 0; i < NU; ++i)
#pragma unroll
        for (int j = 0; j < NV; ++j) {
            off[i * NV + j] = (iu[i] * Wdim + iv[j]) * Cdim;
            sgn[i * NV + j] = fu[i] * fv[j];
        }
    gather<NU * NV>(sat, off, sgn, lane, widx, a, b);
}

__global__ __launch_bounds__(256) void sat_query_kernel(
    const float* __restrict__ sat, const float* __restrict__ x,
    float* __restrict__ out, int n) {
    int wave = (int)((blockIdx.x * blockDim.x + threadIdx.x) >> 6);
    int lane = (int)(threadIdx.x & 63);
    if (wave >= n) return;

    float4 xr = ((const float4*)x)[wave];
    float cu = xr.x, cv = xr.y, d0 = xr.z, d1 = xr.w;

    const float du = 1.0f / 512.0f;  // == dv (H == W == 512)

    float su = cu - d0 * 0.5f, eu = cu + d0 * 0.5f;
    float sv = cv - d1 * 0.5f, ev = cv + d1 * 0.5f;
    float nsu = (d0 < 0.0f) ? eu : su, neu = (d0 < 0.0f) ? su : eu;
    float nsv = (d1 < 0.0f) ? ev : sv, nev = (d1 < 0.0f) ? sv : ev;
    nsu -= floorf(nsu); neu -= floorf(neu);
    nsv -= floorf(nsv); nev -= floorf(nev);

    bool wx = nsu > neu;  // u-axis wraps
    bool wy = nsv > nev;  // v-axis wraps

    // Axis difference operators. Third entry (bru/brv = 1 - du/2 -> texel 511,
    // always in-bounds) participates only when that axis wraps.
    int iu[3]; float fu[3];
    axis_prep(neu,       1.0f, iu[0], fu[0]);
    axis_prep(nsu - du, -1.0f, iu[1], fu[1]);
    iu[2] = Hdim - 1; fu[2] = 1.0f;

    int iv[3]; float fv[3];
    axis_prep(nev,       1.0f, iv[0], fv[0]);
    axis_prep(nsv - du, -1.0f, iv[1], fv[1]);
    iv[2] = Wdim - 1; fv[2] = 1.0f;

    f32x4 acc_a = {0.f, 0.f, 0.f, 0.f};
    f32x4 acc_b = {0.f, 0.f, 0.f, 0.f};
    int widx = (lane & 7) + 64;  // in-row, replicated tail index

    if (!wx && !wy) {
        run_case<2, 2>(sat, iu, fu, iv, fv, lane, widx, acc_a, acc_b);
    } else if (wx && !wy) {
        run_case<3, 2>(sat, iu, fu, iv, fv, lane, widx, acc_a, acc_b);
    } else if (!wx && wy) {
        run_case<2, 3>(sat, iu, fu, iv, fv, lane, widx, acc_a, acc_b);
    } else {
        run_case<3, 3>(sat, iu, fu, iv, fv, lane, widx, acc_a, acc_b);
    }

    // Streaming output: nontemporal so the 151 MB write stream doesn't evict
    // sat from Infinity Cache (sat is 302 MB vs 256 MB L3 -> retention matters).
    f32x4* __restrict__ orow = (f32x4*)(out + (size_t)wave * Cdim);
    __builtin_nontemporal_store(acc_a, orow + lane);
    if (lane < 8) __builtin_nontemporal_store(acc_b, orow + lane + 64);
}

extern "C" void kernel_launch(void* const* d_in, const int* in_sizes, int n_in,
                              void* d_out, int out_size, void* d_ws, size_t ws_size,
                              hipStream_t stream) {
    const float* sat = (const float*)d_in[0];
    const float* x   = (const float*)d_in[1];
    // d_in[2]=start_idx (-1), d_in[3]=len_idx: out_size == N*288 pins the
    // no-slice path, so they are ignored.
    float* out = (float*)d_out;
    int n = in_sizes[1] / 4;  // x is (N,4)

    int rows_per_block = 4;  // 256 threads = 4 waves
    int blocks = (n + rows_per_block - 1) / rows_per_block;
    sat_query_kernel<<<dim3(blocks), dim3(256), 0, stream>>>(sat, x, out, n);
}